// Round 2
// baseline (578.445 us; speedup 1.0000x reference)
//
#include <hip/hip_runtime.h>
#include <hip/hip_bf16.h>
#include <cstdint>
#include <cstddef>

// ---------- types ----------
typedef short bf16x8 __attribute__((ext_vector_type(8)));     // 8 bf16 in 4 VGPRs
typedef float f32x4 __attribute__((ext_vector_type(4)));
typedef unsigned short u16x4 __attribute__((ext_vector_type(4)));

__device__ __forceinline__ unsigned short f2bf(float f) {
  unsigned int u = __builtin_bit_cast(unsigned int, f);
  u = (u + 0x7FFFu + ((u >> 16) & 1u)) >> 16;   // RNE
  return (unsigned short)u;
}

__device__ __forceinline__ f32x4 mfma16x16x32(bf16x8 a, bf16x8 b, f32x4 c) {
  return __builtin_amdgcn_mfma_f32_16x16x32_bf16(a, b, c, 0, 0, 0);
}

// ---------- f32 -> bf16 conversion ----------
__global__ __launch_bounds__(256) void cvt_f32_bf16(const float* __restrict__ src,
                                                    unsigned short* __restrict__ dst, int n) {
  int i = (blockIdx.x * 256 + threadIdx.x) * 4;
  if (i + 3 < n) {
    float4 v = *reinterpret_cast<const float4*>(src + i);
    u16x4 o;
    o[0] = f2bf(v.x); o[1] = f2bf(v.y); o[2] = f2bf(v.z); o[3] = f2bf(v.w);
    *reinterpret_cast<u16x4*>(dst + i) = o;
  }
}

// ---------- GEMM: C[M,N] = A[M,K] * Bw[N,K]^T  (bf16 in, f32 accum) ----------
// m97-style: 128x128 tile, BK=32, 4 waves (2x2), global_load_lds width-16 staging.
template <int OUTF32>
__global__ __launch_bounds__(256) void gemm_bt(const unsigned short* __restrict__ A,
                                               const unsigned short* __restrict__ Bw,
                                               void* __restrict__ Cp,
                                               int M, int N, int K) {
  __shared__ unsigned short As[128 * 32];
  __shared__ unsigned short Bs[128 * 32];
  const int tid  = threadIdx.x;
  const int lane = tid & 63, wid = tid >> 6;
  const int g = lane >> 4, cc = lane & 15;
  const int wr = wid >> 1, wc = wid & 1;
  const int m0 = blockIdx.y * 128, n0 = blockIdx.x * 128;
  const int arow = tid >> 2;          // 0..63
  const int acol = (tid & 3) * 8;     // 0,8,16,24

  const unsigned short* gA = A  + (size_t)(m0 + arow) * K + acol;
  const unsigned short* gB = Bw + (size_t)(n0 + arow) * K + acol;

  f32x4 acc[4][4];
#pragma unroll
  for (int i = 0; i < 4; ++i)
#pragma unroll
    for (int j = 0; j < 4; ++j) acc[i][j] = f32x4{0.f, 0.f, 0.f, 0.f};

  for (int k0 = 0; k0 < K; k0 += 32) {
    // stage A,B tiles: 4 x (256 lanes x 16B). LDS dest = wave-uniform base + lane*16.
    __builtin_amdgcn_global_load_lds(
        (const __attribute__((address_space(1))) void*)(gA + k0),
        (__attribute__((address_space(3))) void*)(As + wid * 512), 16, 0, 0);
    __builtin_amdgcn_global_load_lds(
        (const __attribute__((address_space(1))) void*)(gA + (size_t)64 * K + k0),
        (__attribute__((address_space(3))) void*)(As + 2048 + wid * 512), 16, 0, 0);
    __builtin_amdgcn_global_load_lds(
        (const __attribute__((address_space(1))) void*)(gB + k0),
        (__attribute__((address_space(3))) void*)(Bs + wid * 512), 16, 0, 0);
    __builtin_amdgcn_global_load_lds(
        (const __attribute__((address_space(1))) void*)(gB + (size_t)64 * K + k0),
        (__attribute__((address_space(3))) void*)(Bs + 2048 + wid * 512), 16, 0, 0);
    __syncthreads();   // drains vmcnt -> tiles visible

    bf16x8 af[4], bfv[4];
#pragma unroll
    for (int mi = 0; mi < 4; ++mi)
      af[mi] = *reinterpret_cast<const bf16x8*>(As + (wr * 64 + mi * 16 + cc) * 32 + g * 8);
#pragma unroll
    for (int ni = 0; ni < 4; ++ni)
      bfv[ni] = *reinterpret_cast<const bf16x8*>(Bs + (wc * 64 + ni * 16 + cc) * 32 + g * 8);
#pragma unroll
    for (int mi = 0; mi < 4; ++mi)
#pragma unroll
      for (int ni = 0; ni < 4; ++ni)
        acc[mi][ni] = mfma16x16x32(af[mi], bfv[ni], acc[mi][ni]);
    __syncthreads();   // everyone done reading before next overwrite
  }

  // epilogue: D[i][j]: row = (lane>>4)*4 + r, col = lane&15  (m89/m91-verified)
#pragma unroll
  for (int mi = 0; mi < 4; ++mi) {
#pragma unroll
    for (int ni = 0; ni < 4; ++ni) {
#pragma unroll
      for (int r = 0; r < 4; ++r) {
        const int row = m0 + wr * 64 + mi * 16 + g * 4 + r;
        const int col = n0 + wc * 64 + ni * 16 + cc;
        if (OUTF32)
          reinterpret_cast<float*>(Cp)[(size_t)row * N + col] = acc[mi][ni][r];
        else
          reinterpret_cast<unsigned short*>(Cp)[(size_t)row * N + col] = f2bf(acc[mi][ni][r]);
      }
    }
  }
}

// ---------- causal flash attention ----------
// Layouts: Q,K,V,O are [B,S,1024] bf16, col = h*64 + d.
// One wave = 16 q-rows. Swapped QK^T: S^T = mfma(K-rows, Q-rows) so per-q softmax
// reduction is in-lane(4) + shfl_xor(16) + shfl_xor(32); lane (g,c) reg r holds
// S^T[kv = kvb + 4g + r][q = qb + c].
__global__ __launch_bounds__(256) void attn_fwd(const unsigned short* __restrict__ Q,
                                                const unsigned short* __restrict__ K,
                                                const unsigned short* __restrict__ V,
                                                unsigned short* __restrict__ O) {
  constexpr int S = 2048, DM = 1024, DH = 64;
  const int tid  = threadIdx.x;
  const int lane = tid & 63, wid = tid >> 6;
  const int g = lane >> 4, cc = lane & 15;
  const int bq = blockIdx.x & 31;          // S/64 = 32
  const int h  = (blockIdx.x >> 5) & 15;
  const int b  = blockIdx.x >> 9;
  const int qb = bq * 64 + wid * 16;

  const size_t base = (size_t)b * S * DM + (size_t)h * DH;

  const unsigned short* Qrow = Q + base + (size_t)(qb + cc) * DM;
  const bf16x8 q0 = *reinterpret_cast<const bf16x8*>(Qrow + g * 8);
  const bf16x8 q1 = *reinterpret_cast<const bf16x8*>(Qrow + 32 + g * 8);

  float m_st = -1e30f, l_st = 0.f;
  f32x4 accd[4];
#pragma unroll
  for (int dn = 0; dn < 4; ++dn) accd[dn] = f32x4{0.f, 0.f, 0.f, 0.f};

  const int qidx = qb + cc;
  const int nkv  = qb + 16;                // keys 0..qb+15
  for (int kv0 = 0; kv0 < nkv; kv0 += 32) {
    const bool t1v = (kv0 + 16) < nkv;

    // --- QK^T (S^T form), two 16-kv subtiles ---
    const unsigned short* Krow = K + base + (size_t)(kv0 + cc) * DM;
    f32x4 s0 = f32x4{0.f, 0.f, 0.f, 0.f};
    s0 = mfma16x16x32(*reinterpret_cast<const bf16x8*>(Krow + g * 8), q0, s0);
    s0 = mfma16x16x32(*reinterpret_cast<const bf16x8*>(Krow + 32 + g * 8), q1, s0);
    f32x4 s1 = f32x4{0.f, 0.f, 0.f, 0.f};
    if (t1v) {
      const unsigned short* Krow1 = Krow + (size_t)16 * DM;
      s1 = mfma16x16x32(*reinterpret_cast<const bf16x8*>(Krow1 + g * 8), q0, s1);
      s1 = mfma16x16x32(*reinterpret_cast<const bf16x8*>(Krow1 + 32 + g * 8), q1, s1);
    }

    // --- scale + causal mask ---
    float sv0[4], sv1[4];
#pragma unroll
    for (int r = 0; r < 4; ++r) {
      const int kv  = kv0 + g * 4 + r;
      sv0[r] = (kv <= qidx) ? s0[r] * 0.125f : -1e30f;
      const int kv1 = kv + 16;
      sv1[r] = (t1v && kv1 <= qidx) ? s1[r] * 0.125f : -1e30f;
    }

    // --- online softmax stats (per q = qb+cc) ---
    float tm = fmaxf(fmaxf(fmaxf(sv0[0], sv0[1]), fmaxf(sv0[2], sv0[3])),
                     fmaxf(fmaxf(sv1[0], sv1[1]), fmaxf(sv1[2], sv1[3])));
    tm = fmaxf(tm, __shfl_xor(tm, 16));
    tm = fmaxf(tm, __shfl_xor(tm, 32));
    const float m_new = fmaxf(m_st, tm);
    const float corr  = __expf(m_st - m_new);
    float p0[4], p1[4], ls = 0.f;
#pragma unroll
    for (int r = 0; r < 4; ++r) { p0[r] = __expf(sv0[r] - m_new); ls += p0[r]; }
#pragma unroll
    for (int r = 0; r < 4; ++r) { p1[r] = __expf(sv1[r] - m_new); ls += p1[r]; }
    ls += __shfl_xor(ls, 16);
    ls += __shfl_xor(ls, 32);
    l_st = l_st * corr + ls;
    m_st = m_new;

    // --- rescale O accumulator (O rows are q = qb + g*4 + r) ---
#pragma unroll
    for (int r = 0; r < 4; ++r) {
      const float cr = __shfl(corr, g * 4 + r);
#pragma unroll
      for (int dn = 0; dn < 4; ++dn) accd[dn][r] *= cr;
    }

    // --- build PV A-frag: need P[q = qb+cc][kvloc = g*8 + j] ---
    bf16x8 pa;
#pragma unroll
    for (int j = 0; j < 8; ++j) {
      const int sl = (((2 * g + (j >> 2)) & 3) << 4) | cc;
      const float v0 = __shfl(p0[j & 3], sl);
      const float v1 = __shfl(p1[j & 3], sl);
      const float pv = (lane & 32) ? v1 : v0;   // subtile t' = g>>1
      pa[j] = (short)f2bf(pv);
    }

    // --- PV: O[16q][64d] += P[16q][32kv] @ V[32kv][64d] ---
    const unsigned short* Vrow = V + base + (size_t)(kv0 + g * 8) * DM;
#pragma unroll
    for (int dn = 0; dn < 4; ++dn) {
      bf16x8 bv;
#pragma unroll
      for (int j = 0; j < 8; ++j) bv[j] = (short)Vrow[(size_t)j * DM + dn * 16 + cc];
      accd[dn] = mfma16x16x32(pa, bv, accd[dn]);
    }
  }

  // --- epilogue: normalize and store ---
#pragma unroll
  for (int r = 0; r < 4; ++r) {
    const float li  = __shfl(l_st, g * 4 + r);
    const float inv = 1.0f / li;
    unsigned short* Orow = O + base + (size_t)(qb + g * 4 + r) * DM;
#pragma unroll
    for (int dn = 0; dn < 4; ++dn)
      Orow[dn * 16 + cc] = f2bf(accd[dn][r] * inv);
  }
}

// ---------- launch ----------
extern "C" void kernel_launch(void* const* d_in, const int* in_sizes, int n_in,
                              void* d_out, int out_size, void* d_ws, size_t ws_size,
                              hipStream_t stream) {
  (void)in_sizes; (void)n_in; (void)out_size; (void)ws_size;
  constexpr int Bx = 4, S = 2048, DM = 1024;
  constexpr int M = Bx * S;          // 8192
  constexpr size_t XEL = (size_t)M * DM;       // 8388608
  constexpr size_t WEL = (size_t)DM * DM;      // 1048576

  const float* Wq = (const float*)d_in[1];
  const float* Wk = (const float*)d_in[2];
  const float* Wv = (const float*)d_in[3];
  const float* Wo = (const float*)d_in[4];
  const float* Xf = (const float*)d_in[5];
  float* out = (float*)d_out;

  char* ws = (char*)d_ws;
  unsigned short* Xbf = (unsigned short*)(ws + 0);          // 16 MB (reused as attn-out)
  unsigned short* Wqb = (unsigned short*)(ws + 16777216);
  unsigned short* Wkb = (unsigned short*)(ws + 18874368);
  unsigned short* Wvb = (unsigned short*)(ws + 20971520);
  unsigned short* Wob = (unsigned short*)(ws + 23068672);
  unsigned short* Qb  = (unsigned short*)(ws + 25165824);
  unsigned short* Kb  = (unsigned short*)(ws + 41943040);
  unsigned short* Vb  = (unsigned short*)(ws + 58720256);
  unsigned short* Ob  = Xbf;   // alias: X no longer needed after V projection

  // 1) convert inputs to bf16
  cvt_f32_bf16<<<(int)(XEL / 1024), 256, 0, stream>>>(Xf, Xbf, (int)XEL);
  cvt_f32_bf16<<<(int)(WEL / 1024), 256, 0, stream>>>(Wq, Wqb, (int)WEL);
  cvt_f32_bf16<<<(int)(WEL / 1024), 256, 0, stream>>>(Wk, Wkb, (int)WEL);
  cvt_f32_bf16<<<(int)(WEL / 1024), 256, 0, stream>>>(Wv, Wvb, (int)WEL);
  cvt_f32_bf16<<<(int)(WEL / 1024), 256, 0, stream>>>(Wo, Wob, (int)WEL);

  // 2) Q/K/V projections (bf16 out)
  dim3 gg(DM / 128, M / 128);   // (8, 64)
  gemm_bt<0><<<gg, 256, 0, stream>>>(Xbf, Wqb, Qb, M, DM, DM);
  gemm_bt<0><<<gg, 256, 0, stream>>>(Xbf, Wkb, Kb, M, DM, DM);
  gemm_bt<0><<<gg, 256, 0, stream>>>(Xbf, Wvb, Vb, M, DM, DM);

  // 3) causal flash attention (writes Ob, aliasing Xbf)
  attn_fwd<<<Bx * 16 * (S / 64), 256, 0, stream>>>(Qb, Kb, Vb, Ob);

  // 4) output projection (f32 out)
  gemm_bt<1><<<gg, 256, 0, stream>>>(Ob, Wob, out, M, DM, DM);
}